// Round 5
// baseline (404.436 us; speedup 1.0000x reference)
//
#include <hip/hip_runtime.h>
#include <hip/hip_bf16.h>

#define BATCH 4
#define SEQ   4096
#define EMB   1024
#define PDIM  128

using short8   = __attribute__((ext_vector_type(8))) short;
using ushort8  = __attribute__((ext_vector_type(8))) unsigned short;
using ushort4v = __attribute__((ext_vector_type(4))) unsigned short;
using float4v  = __attribute__((ext_vector_type(4))) float;
using float16v = __attribute__((ext_vector_type(16))) float;

__device__ __forceinline__ unsigned short f2bf(float f) {
  union { float f; unsigned int u; } x; x.f = f;
  unsigned int r = x.u + 0x7fffu + ((x.u >> 16) & 1u);   // round-to-nearest-even
  return (unsigned short)(r >> 16);
}

// async global->LDS, 16B per lane; LDS dest = wave-uniform base + lane*16
__device__ __forceinline__ void gld_lds16(const unsigned short* g, unsigned short* l) {
  __builtin_amdgcn_global_load_lds(
      (__attribute__((address_space(1))) void*)(g),
      (__attribute__((address_space(3))) void*)(l), 16, 0, 0);
}

// ---------- x prep: x (B,S,E) fp32 -> x_bf (B*S,E) bf16 AND xT (B,E,S) bf16 ----------
__global__ void xprep_kernel(const float* __restrict__ src,
                             unsigned short* __restrict__ rm,
                             unsigned short* __restrict__ tp) {
  __shared__ float tile[64][65];
  const int tid = threadIdx.x;
  const int z = blockIdx.z;
  const float* s = src + (size_t)z * SEQ * EMB;
  unsigned short* drm = rm + (size_t)z * SEQ * EMB;
  unsigned short* dtp = tp + (size_t)z * SEQ * EMB;
  const int e0 = blockIdx.x * 64, s0 = blockIdx.y * 64;
#pragma unroll
  for (int i = 0; i < 4; i++) {
    int idx = tid + i * 256;
    int sr = idx >> 4, c4 = (idx & 15) * 4;
    float4v v = *(const float4v*)(s + (size_t)(s0 + sr) * EMB + e0 + c4);
    ushort4v o;
    o[0] = f2bf(v[0]); o[1] = f2bf(v[1]); o[2] = f2bf(v[2]); o[3] = f2bf(v[3]);
    *(ushort4v*)(drm + (size_t)(s0 + sr) * EMB + e0 + c4) = o;
    tile[sr][c4] = v[0]; tile[sr][c4 + 1] = v[1];
    tile[sr][c4 + 2] = v[2]; tile[sr][c4 + 3] = v[3];
  }
  __syncthreads();
#pragma unroll
  for (int i = 0; i < 2; i++) {
    int idx = tid + i * 256;
    int e = idx >> 3, sc = idx & 7;
    ushort8 o;
#pragma unroll
    for (int j = 0; j < 8; j++) o[j] = f2bf(tile[sc * 8 + j][e]);
    *(ushort8*)(dtp + (size_t)(e0 + e) * SEQ + s0 + sc * 8) = o;
  }
}

// ---------- weight prep: Wq/Wk/Wov transpose+cast, bqk concat, lsum zero ----------
__global__ void wprep_kernel(const float* __restrict__ Wq, const float* __restrict__ Wk,
                             const float* __restrict__ Wov,
                             unsigned short* __restrict__ WqkT, unsigned short* __restrict__ WovT,
                             const float* __restrict__ bq, const float* __restrict__ bk,
                             float* __restrict__ bqk, float* __restrict__ lsum) {
  __shared__ float t[32][33];
  const int bid = blockIdx.x, tid = threadIdx.x;
  const int tx = tid & 31, ty = tid >> 5;
  const float* src; unsigned short* dst; int C, bx, by;
  if (bid < 128)        { src = Wq;  dst = WqkT;                       C = PDIM; int b = bid;        bx = b & 3;  by = b >> 2; }
  else if (bid < 256)   { src = Wk;  dst = WqkT + (size_t)PDIM * EMB;  C = PDIM; int b = bid - 128;  bx = b & 3;  by = b >> 2; }
  else if (bid < 1280)  { src = Wov; dst = WovT;                       C = EMB;  int b = bid - 256;  bx = b & 31; by = b >> 5; }
  else if (bid == 1280) {
    if (tid < 2 * PDIM) bqk[tid] = (tid < PDIM) ? bq[tid] : bk[tid - PDIM];
    return;
  } else {
    lsum[(bid - 1281) * 256 + tid] = 0.f;
    return;
  }
  const int c0 = bx * 32, r0 = by * 32;
#pragma unroll
  for (int i = 0; i < 32; i += 8)
    t[ty + i][tx] = src[(size_t)(r0 + ty + i) * C + c0 + tx];
  __syncthreads();
#pragma unroll
  for (int i = 0; i < 32; i += 8)
    dst[(size_t)(c0 + ty + i) * EMB + r0 + tx] = f2bf(t[tx][ty + i]);
}

// ---------- GEMM: C = f(A @ Bt^T), 128 x NT tile, BK=32, mfma 32x32x16 ----------
// Double-buffered single-barrier ping-pong: stage(k+1) issued right after the
// barrier, in flight during compute(k); next barrier's vmcnt(0) drain overlaps.
// LDS swizzle: 32-ushort rows, 4 slots of 16B; slot s of row r holds global
// k-chunk s ^ f(r), f(r) = ((r>>1)&3) ^ ((r>>3)&3) -> conflict-free for both
// consecutive-8 and stride-8 lane phases (worst 2-way = free, m136).
// mode: 0 = fp32 acc+bias | 1 = bf16 exp(acc*scale) + atomic rowsum -> lsum
//       2 = bf16 acc / lsum[row]                    | 3 = bf16 acc+bias
template <int NT>
__global__ __launch_bounds__(256, 2) void gemm_kernel(
    const unsigned short* __restrict__ A, int lda, size_t saz,
    const unsigned short* __restrict__ Bt, int ldb, size_t sbz,
    void* __restrict__ Cv, int ldc, size_t scz,
    int K, const float* __restrict__ bias,
    float* __restrict__ lsum, int slz,
    float scale, int mode) {
  constexpr int NTW = NT / 64;   // 32-wide n-tiles per wave
  constexpr int BG  = NT / 64;   // 16-row B staging groups per wave
  __shared__ __attribute__((aligned(16))) unsigned short As[2][128 * 32];
  __shared__ __attribute__((aligned(16))) unsigned short Bs[2][NT * 32];
  const int tid = threadIdx.x;
  const int wave = tid >> 6, lane = tid & 63;
  const int m0 = blockIdx.x * 128, n0 = blockIdx.y * NT;
  const int z = blockIdx.z;
  const int mq = (wave >> 1) * 64, nq = (wave & 1) * (NT / 2);

  A  += (size_t)z * saz;
  Bt += (size_t)z * sbz;

  // staging: 16-row groups; lane -> row sr = lane>>2, slot sl4 = lane&3
  const int sr = lane >> 2, sl4 = lane & 3;
  const unsigned short* Ag[2]; int Ao[2];
#pragma unroll
  for (int j = 0; j < 2; j++) {
    int g = wave * 2 + j;
    int r = g * 16 + sr;
    int f = ((r >> 1) & 3) ^ ((r >> 3) & 3);
    Ag[j] = A + (size_t)(m0 + r) * lda + ((sl4 ^ f) << 3);
    Ao[j] = g * 512;
  }
  const unsigned short* Bg[BG]; int Bo[BG];
#pragma unroll
  for (int j = 0; j < BG; j++) {
    int g = wave * BG + j;
    int r = g * 16 + sr;
    int f = ((r >> 1) & 3) ^ ((r >> 3) & 3);
    Bg[j] = Bt + (size_t)(n0 + r) * ldb + ((sl4 ^ f) << 3);
    Bo[j] = g * 512;
  }

  float16v acc[2][NTW];
#pragma unroll
  for (int i = 0; i < 2; i++)
#pragma unroll
    for (int j = 0; j < NTW; j++)
#pragma unroll
      for (int r = 0; r < 16; r++) acc[i][j][r] = 0.f;

  const int rt = lane & 31;   // row (A) / col (B) within a 32-tile
  const int h  = lane >> 5;   // k-half: k = 8*h + j
  const int fr = ((rt >> 1) & 3) ^ ((rt >> 3) & 3);

  auto stage = [&](int k0, int buf) {
#pragma unroll
    for (int j = 0; j < 2; j++) gld_lds16(Ag[j] + k0, &As[buf][Ao[j]]);
#pragma unroll
    for (int j = 0; j < BG; j++) gld_lds16(Bg[j] + k0, &Bs[buf][Bo[j]]);
  };
  auto compute = [&](int buf) {
#pragma unroll
    for (int kt = 0; kt < 2; kt++) {
      const int sl = (((kt * 2 + h) ^ fr)) << 3;
      short8 af[2], bfr[NTW];
#pragma unroll
      for (int mt = 0; mt < 2; mt++)
        af[mt] = *(const short8*)(&As[buf][(mq + mt * 32 + rt) * 32 + sl]);
#pragma unroll
      for (int nt = 0; nt < NTW; nt++)
        bfr[nt] = *(const short8*)(&Bs[buf][(nq + nt * 32 + rt) * 32 + sl]);
#pragma unroll
      for (int mt = 0; mt < 2; mt++)
#pragma unroll
        for (int nt = 0; nt < NTW; nt++)
          acc[mt][nt] = __builtin_amdgcn_mfma_f32_32x32x16_bf16(af[mt], bfr[nt], acc[mt][nt], 0, 0, 0);
    }
  };

  stage(0, 0);
  for (int k0 = 0; k0 < K; k0 += 64) {
    __syncthreads();
    if (k0 + 32 < K) stage(k0 + 32, 1);
    compute(0);
    __syncthreads();
    if (k0 + 64 < K) stage(k0 + 64, 0);
    compute(1);
  }

  // C/D layout: col = rt, row = (reg&3) + 8*(reg>>2) + 4*h
  if (mode == 1) {
    unsigned short* Cb = (unsigned short*)Cv + (size_t)z * scz;
    float* ls = lsum + (size_t)z * slz;
#pragma unroll
    for (int mt = 0; mt < 2; mt++) {
      float rs[16];
#pragma unroll
      for (int r = 0; r < 16; r++) rs[r] = 0.f;
#pragma unroll
      for (int r = 0; r < 16; r++) {
        int gm = m0 + mq + mt * 32 + (r & 3) + 8 * (r >> 2) + 4 * h;
#pragma unroll
        for (int nt = 0; nt < NTW; nt++) {
          float e = __expf(acc[mt][nt][r] * scale);
          Cb[(size_t)gm * ldc + n0 + nq + nt * 32 + rt] = f2bf(e);
          rs[r] += e;
        }
      }
#pragma unroll
      for (int r = 0; r < 16; r++) {
        float s = rs[r];
#pragma unroll
        for (int o = 1; o < 32; o <<= 1) s += __shfl_xor(s, o);
        rs[r] = s;
      }
      if (rt == 0)
#pragma unroll
        for (int r = 0; r < 16; r++)
          atomicAdd(&ls[m0 + mq + mt * 32 + (r & 3) + 8 * (r >> 2) + 4 * h], rs[r]);
    }
  } else if (mode == 2) {
    unsigned short* Cb = (unsigned short*)Cv + (size_t)z * scz;
    const float* ls = lsum + (size_t)z * slz;
#pragma unroll
    for (int mt = 0; mt < 2; mt++)
#pragma unroll
      for (int r = 0; r < 16; r++) {
        int gm = m0 + mq + mt * 32 + (r & 3) + 8 * (r >> 2) + 4 * h;
        float li = 1.f / ls[gm];
#pragma unroll
        for (int nt = 0; nt < NTW; nt++)
          Cb[(size_t)gm * ldc + n0 + nq + nt * 32 + rt] = f2bf(acc[mt][nt][r] * li);
      }
  } else {
    float* Cf = (float*)Cv + (size_t)z * scz;
    unsigned short* Cb = (unsigned short*)Cv + (size_t)z * scz;
    float bv[NTW];
#pragma unroll
    for (int nt = 0; nt < NTW; nt++) bv[nt] = bias[n0 + nq + nt * 32 + rt];
#pragma unroll
    for (int mt = 0; mt < 2; mt++)
#pragma unroll
      for (int r = 0; r < 16; r++) {
        int gm = m0 + mq + mt * 32 + (r & 3) + 8 * (r >> 2) + 4 * h;
#pragma unroll
        for (int nt = 0; nt < NTW; nt++) {
          float v = acc[mt][nt][r] + bv[nt];
          if (mode == 0) Cf[(size_t)gm * ldc + n0 + nq + nt * 32 + rt] = v;
          else           Cb[(size_t)gm * ldc + n0 + nq + nt * 32 + rt] = f2bf(v);
        }
      }
  }
}

extern "C" void kernel_launch(void* const* d_in, const int* in_sizes, int n_in,
                              void* d_out, int out_size, void* d_ws, size_t ws_size,
                              hipStream_t stream) {
  const float* x   = (const float*)d_in[0];
  const float* Wq  = (const float*)d_in[1];
  const float* bq  = (const float*)d_in[2];
  const float* Wk  = (const float*)d_in[3];
  const float* bk  = (const float*)d_in[4];
  const float* Wov = (const float*)d_in[5];
  const float* bov = (const float*)d_in[6];
  float* out = (float*)d_out;

  char* ws = (char*)d_ws;
  size_t off = 0;
  auto alloc = [&](size_t bytes) {
    char* p = ws + off;
    off += (bytes + 255) & ~(size_t)255;
    return p;
  };
  const int M = BATCH * SEQ;  // 16384
  unsigned short* x_bf = (unsigned short*)alloc((size_t)M * EMB * 2);
  unsigned short* xT   = (unsigned short*)alloc((size_t)M * EMB * 2);
  unsigned short* WqkT = (unsigned short*)alloc((size_t)2 * PDIM * EMB * 2);
  unsigned short* WovT = (unsigned short*)alloc((size_t)EMB * EMB * 2);
  float*          bqk  = (float*)alloc(2 * PDIM * sizeof(float));
  unsigned short* qk   = (unsigned short*)alloc((size_t)M * 2 * PDIM * 2);
  float*          linv = (float*)alloc((size_t)M * sizeof(float));
  unsigned short* ctx  = (unsigned short*)alloc((size_t)M * EMB * 2);
  const size_t pslot = (size_t)SEQ * SEQ * 2;
  unsigned short* P = (unsigned short*)(ws + off);
  size_t rem = ws_size > off ? ws_size - off : 0;
  int g = (rem >= 4 * pslot) ? 4 : (rem >= 2 * pslot) ? 2 : 1;

  // ---- prep (2 launches) ----
  xprep_kernel<<<dim3(EMB / 64, SEQ / 64, BATCH), 256, 0, stream>>>(x, x_bf, xT);
  wprep_kernel<<<dim3(1345), 256, 0, stream>>>(Wq, Wk, Wov, WqkT, WovT, bq, bk, bqk, linv);

  // ---- qk projection: (16384 x 1024) @ (256 x 1024)^T + bqk -> bf16 ----
  gemm_kernel<128><<<dim3(M / 128, 2, 1), 256, 0, stream>>>(
      x_bf, EMB, 0, WqkT, EMB, 0, qk, 2 * PDIM, 0, EMB, bqk, nullptr, 0, 1.f, 3);

  const float qscale = 0.08838834764831845f;  // 1/sqrt(128)
  for (int b0 = 0; b0 < BATCH; b0 += g) {
    int gg = (b0 + g <= BATCH) ? g : (BATCH - b0);
    // S-GEMM: P~ = exp(scale * q @ k^T) + fused atomic rowsum
    gemm_kernel<256><<<dim3(SEQ / 128, SEQ / 256, gg), 256, 0, stream>>>(
        qk + (size_t)b0 * SEQ * 2 * PDIM, 2 * PDIM, (size_t)SEQ * 2 * PDIM,
        qk + (size_t)b0 * SEQ * 2 * PDIM + PDIM, 2 * PDIM, (size_t)SEQ * 2 * PDIM,
        P, SEQ, (size_t)SEQ * SEQ,
        PDIM, nullptr, linv + (size_t)b0 * SEQ, SEQ, qscale, 1);
    // PV: ctx = (P~ @ xT^T) / l
    gemm_kernel<256><<<dim3(SEQ / 128, EMB / 256, gg), 256, 0, stream>>>(
        P, SEQ, (size_t)SEQ * SEQ,
        xT + (size_t)b0 * EMB * SEQ, SEQ, (size_t)EMB * SEQ,
        ctx + (size_t)b0 * SEQ * EMB, EMB, (size_t)SEQ * EMB,
        SEQ, nullptr, linv + (size_t)b0 * SEQ, SEQ, 1.f, 2);
  }

  // ---- out projection: out = ctx @ WovT^T + bov (fp32) ----
  gemm_kernel<256><<<dim3(M / 128, EMB / 256, 1), 256, 0, stream>>>(
      ctx, EMB, 0, WovT, EMB, 0, out, EMB, 0, EMB, bov, nullptr, 0, 1.f, 0);
}